// Round 6
// baseline (387.726 us; speedup 1.0000x reference)
//
#include <hip/hip_runtime.h>
#include <hip/hip_bf16.h>

#define NN 8192      // nodes
#define FIN 512      // in features
#define HD 256       // hidden
#define DD 64        // embedding
#define NE 262144    // edges
#define BCAP 128     // fixed bucket capacity per row (max degree ~60; 17-sigma margin)

typedef __bf16 bf16_t;
typedef __bf16 bf16x8 __attribute__((ext_vector_type(8)));
typedef __bf16 bf16x4 __attribute__((ext_vector_type(4)));
typedef float f32x4 __attribute__((ext_vector_type(4)));

// ---------------- fused prep: cast x (16B stores), transpose W1/W2 (8B stores), zero deg ----------------
// grid = 2048 (x) + 128 (W1) + 16 (W2) + 8 (deg) blocks of 256
__global__ __launch_bounds__(256) void prep_kernel(const float* __restrict__ x, bf16_t* __restrict__ x_b,
                                                   const float* __restrict__ W1, bf16_t* __restrict__ w1t,
                                                   const float* __restrict__ W2, bf16_t* __restrict__ w2t,
                                                   int* __restrict__ deg) {
    int b = blockIdx.x;
    if (b < 2048) {
        int i = (b * 256 + threadIdx.x) * 8;
        float4 v0 = *reinterpret_cast<const float4*>(x + i);
        float4 v1 = *reinterpret_cast<const float4*>(x + i + 4);
        bf16x8 o = {(bf16_t)v0.x, (bf16_t)v0.y, (bf16_t)v0.z, (bf16_t)v0.w,
                    (bf16_t)v1.x, (bf16_t)v1.y, (bf16_t)v1.z, (bf16_t)v1.w};
        *reinterpret_cast<bf16x8*>(x_b + i) = o;
    } else if (b < 2048 + 128) {
        // W1 [FIN=512, HD=256] -> w1t [HD][FIN]; o = c*512 + r
        int o4 = ((b - 2048) * 256 + threadIdx.x) * 4;
        int r = o4 & 511;
        int c = o4 >> 9;
        bf16x4 o = {(bf16_t)W1[(r + 0) * HD + c], (bf16_t)W1[(r + 1) * HD + c],
                    (bf16_t)W1[(r + 2) * HD + c], (bf16_t)W1[(r + 3) * HD + c]};
        *reinterpret_cast<bf16x4*>(w1t + o4) = o;
    } else if (b < 2048 + 128 + 16) {
        // W2 [HD=256, DD=64] -> w2t [DD][HD]; o = c*256 + r
        int o4 = ((b - 2048 - 128) * 256 + threadIdx.x) * 4;
        int r = o4 & 255;
        int c = o4 >> 8;
        bf16x4 o = {(bf16_t)W2[(r + 0) * DD + c], (bf16_t)W2[(r + 1) * DD + c],
                    (bf16_t)W2[(r + 2) * DD + c], (bf16_t)W2[(r + 3) * DD + c]};
        *reinterpret_cast<bf16x4*>(w2t + o4) = o;
    } else {
        int o = ((b - 2048 - 128 - 16) * 256 + threadIdx.x) * 4;
        *reinterpret_cast<int4*>(deg + o) = {0, 0, 0, 0};
    }
}

// ---------------- fused node 2: GEMM1 (blocks 0..511) + bucket scatter (blocks 512..1535) ----------------
// GEMM1: h0 = x_b @ w1t^T + b1, bf16 out. tile 64x64, MW=1 layout.
__global__ __launch_bounds__(256) void gemm1_scatter(const bf16_t* __restrict__ A,
                                                     const bf16_t* __restrict__ Bt,
                                                     const float* __restrict__ bias,
                                                     bf16_t* __restrict__ C,
                                                     const int* __restrict__ rows, const int* __restrict__ cols,
                                                     const float* __restrict__ vals,
                                                     int* __restrict__ deg, int* __restrict__ scol,
                                                     float* __restrict__ sval) {
    int b = blockIdx.x;
    if (b >= 512) {
        int e = (b - 512) * 256 + threadIdx.x;
        int r = rows[e];
        int p = atomicAdd(&deg[r], 1);
        scol[r * BCAP + p] = cols[e];
        sval[r * BCAP + p] = vals[e];
        return;
    }
    const int K = FIN, N = HD;
    int wave = threadIdx.x >> 6;
    int lane = threadIdx.x & 63;
    int lr = lane & 15;
    int lq = lane >> 4;
    int m0 = (b & 127) * 64 + wave * 16;
    int n0 = (b >> 7) * 64;

    f32x4 acc[4];
#pragma unroll
    for (int t = 0; t < 4; t++) acc[t] = {0.f, 0.f, 0.f, 0.f};

    const bf16_t* Abase = A + (size_t)(m0 + lr) * K + lq * 8;
    const bf16_t* Bbase = Bt + (size_t)(n0 + lr) * K + lq * 8;
    for (int k0 = 0; k0 < K; k0 += 32) {
        bf16x8 a = *reinterpret_cast<const bf16x8*>(Abase + k0);
#pragma unroll
        for (int t = 0; t < 4; t++) {
            bf16x8 bb = *reinterpret_cast<const bf16x8*>(Bbase + (size_t)t * 16 * K + k0);
            acc[t] = __builtin_amdgcn_mfma_f32_16x16x32_bf16(a, bb, acc[t], 0, 0, 0);
        }
    }
#pragma unroll
    for (int t = 0; t < 4; t++) {
        int col = n0 + t * 16 + lr;
        float bv = bias[col];
#pragma unroll
        for (int r = 0; r < 4; r++) {
            int row = m0 + lq * 4 + r;
            C[(size_t)row * N + col] = (bf16_t)(acc[t][r] + bv);
        }
    }
}

// ---------------- SpMM ----------------

// h[r,:] = relu(sum_e val * h0[col,:]); one block per row; 4 waves split edges,
// lane owns 4 features (bf16x4 gather), LDS cross-wave reduce, bf16x4 store.
__global__ __launch_bounds__(256) void spmm_h_kernel(const int* __restrict__ deg,
                                                     const int* __restrict__ scol,
                                                     const float* __restrict__ sval,
                                                     const bf16_t* __restrict__ h0,
                                                     bf16_t* __restrict__ h) {
    int r = blockIdx.x;
    int wv = threadIdx.x >> 6;
    int lane = threadIdx.x & 63;
    int nd = deg[r];
    int base = r * BCAP;
    float a0 = 0.f, a1 = 0.f, a2 = 0.f, a3 = 0.f;
#pragma unroll 2
    for (int e = wv; e < nd; e += 4) {
        int c = scol[base + e];
        float v = sval[base + e];
        bf16x4 hv = *reinterpret_cast<const bf16x4*>(h0 + (size_t)c * HD + lane * 4);
        a0 += v * (float)hv[0];
        a1 += v * (float)hv[1];
        a2 += v * (float)hv[2];
        a3 += v * (float)hv[3];
    }
    __shared__ float red[4][256];
    red[wv][lane * 4 + 0] = a0;
    red[wv][lane * 4 + 1] = a1;
    red[wv][lane * 4 + 2] = a2;
    red[wv][lane * 4 + 3] = a3;
    __syncthreads();
    if (wv == 0) {
        int f = lane * 4;
        bf16x4 o = {(bf16_t)fmaxf(red[0][f + 0] + red[1][f + 0] + red[2][f + 0] + red[3][f + 0], 0.f),
                    (bf16_t)fmaxf(red[0][f + 1] + red[1][f + 1] + red[2][f + 1] + red[3][f + 1], 0.f),
                    (bf16_t)fmaxf(red[0][f + 2] + red[1][f + 2] + red[2][f + 2] + red[3][f + 2], 0.f),
                    (bf16_t)fmaxf(red[0][f + 3] + red[1][f + 3] + red[2][f + 3] + red[3][f + 3], 0.f)};
        *reinterpret_cast<bf16x4*>(h + (size_t)r * HD + f) = o;
    }
}

// z: 4 rows per wave (16-lane subgroups), lane covers 4 cols; vectorized loads/stores.
// grid = NN/16 blocks of 256.
__global__ __launch_bounds__(256) void spmm_z_kernel(const int* __restrict__ deg,
                                                     const int* __restrict__ scol,
                                                     const float* __restrict__ sval,
                                                     const bf16_t* __restrict__ z0,
                                                     float* __restrict__ z_out,
                                                     bf16_t* __restrict__ z_b) {
    int wv = threadIdx.x >> 6;
    int lane = threadIdx.x & 63;
    int lq = lane >> 4;   // subgroup = row select
    int lr = lane & 15;   // col group
    int r = blockIdx.x * 16 + wv * 4 + lq;
    int nd = deg[r];
    int base = r * BCAP;
    float a0 = 0.f, a1 = 0.f, a2 = 0.f, a3 = 0.f;
    for (int e = 0; e < nd; e++) {
        int c = scol[base + e];
        float v = sval[base + e];
        bf16x4 zv = *reinterpret_cast<const bf16x4*>(z0 + (size_t)c * DD + lr * 4);
        a0 += v * (float)zv[0];
        a1 += v * (float)zv[1];
        a2 += v * (float)zv[2];
        a3 += v * (float)zv[3];
    }
    f32x4 of = {a0, a1, a2, a3};
    *reinterpret_cast<f32x4*>(z_out + (size_t)r * DD + lr * 4) = of;
    bf16x4 ob = {(bf16_t)a0, (bf16_t)a1, (bf16_t)a2, (bf16_t)a3};
    *reinterpret_cast<bf16x4*>(z_b + (size_t)r * DD + lr * 4) = ob;
}

// ---------------- MFMA GEMM: C[M,N] = A[M,K] @ Bt[N,K]^T (+bias) ----------------
// ACT: 0 = none(+bias), direct stores. 2 = sigmoid, LDS-transposed float4 stores.
template <int ACT, typename OutT, int MW>
__global__ __launch_bounds__(256) void gemm_bt(const bf16_t* __restrict__ A,
                                               const bf16_t* __restrict__ Bt,
                                               const float* __restrict__ bias,
                                               OutT* __restrict__ C,
                                               int M, int N, int K) {
    int wave = threadIdx.x >> 6;
    int lane = threadIdx.x & 63;
    int lr = lane & 15;
    int lq = lane >> 4;
    int m0 = blockIdx.x * (64 * MW) + wave * (16 * MW);
    int n0 = blockIdx.y * 64;

    f32x4 acc[MW][4];
#pragma unroll
    for (int i = 0; i < MW; i++)
#pragma unroll
        for (int t = 0; t < 4; t++) acc[i][t] = {0.f, 0.f, 0.f, 0.f};

    const bf16_t* Abase = A + (size_t)(m0 + lr) * K + lq * 8;
    const bf16_t* Bbase = Bt + (size_t)(n0 + lr) * K + lq * 8;

    for (int k0 = 0; k0 < K; k0 += 32) {
        bf16x8 a[MW];
#pragma unroll
        for (int i = 0; i < MW; i++)
            a[i] = *reinterpret_cast<const bf16x8*>(Abase + (size_t)i * 16 * K + k0);
#pragma unroll
        for (int t = 0; t < 4; t++) {
            bf16x8 b = *reinterpret_cast<const bf16x8*>(Bbase + (size_t)t * 16 * K + k0);
#pragma unroll
            for (int i = 0; i < MW; i++)
                acc[i][t] = __builtin_amdgcn_mfma_f32_16x16x32_bf16(a[i], b, acc[i][t], 0, 0, 0);
        }
    }

    if (ACT == 2) {
        // Per-wave private LDS transpose; plain float4 stores (R4 A/B: NT hurt).
        __shared__ float ldsT[256 / 64 * 16 * MW][65];
        int rbase = wave * 16 * MW;
#pragma unroll
        for (int i = 0; i < MW; i++)
#pragma unroll
            for (int t = 0; t < 4; t++)
#pragma unroll
                for (int r = 0; r < 4; r++) {
                    float v = acc[i][t][r];
                    v = 1.f / (1.f + __expf(-v));
                    ldsT[rbase + i * 16 + lq * 4 + r][t * 16 + lr] = v;
                }
        int c4 = (lane & 15) * 4;
        int rr = lane >> 4;
#pragma unroll
        for (int j = 0; j < 4 * MW; j++) {
            int row_l = rbase + j * 4 + rr;
            f32x4 v = *reinterpret_cast<const f32x4*>(&ldsT[row_l][c4]);
            size_t gaddr = (size_t)(blockIdx.x * (64 * MW) + row_l) * N + n0 + c4;
            *reinterpret_cast<f32x4*>(&C[gaddr]) = v;
        }
    } else {
#pragma unroll
        for (int i = 0; i < MW; i++) {
#pragma unroll
            for (int t = 0; t < 4; t++) {
                int col = n0 + t * 16 + lr;
                float bv = bias ? bias[col] : 0.f;
#pragma unroll
                for (int r = 0; r < 4; r++) {
                    int row = m0 + i * 16 + lq * 4 + r;
                    C[(size_t)row * N + col] = (OutT)(acc[i][t][r] + bv);
                }
            }
        }
    }
}

// ---------------- launch ----------------

extern "C" void kernel_launch(void* const* d_in, const int* in_sizes, int n_in,
                              void* d_out, int out_size, void* d_ws, size_t ws_size,
                              hipStream_t stream) {
    const float* x   = (const float*)d_in[0];
    const int* rows  = (const int*)d_in[1];
    const int* cols  = (const int*)d_in[2];
    const float* vals = (const float*)d_in[3];
    const float* W1  = (const float*)d_in[4];
    const float* b1  = (const float*)d_in[5];
    const float* W2  = (const float*)d_in[6];
    const float* b2  = (const float*)d_in[7];

    float* out_z   = (float*)d_out;                       // [8192,64]
    float* out_adj = out_z + (size_t)NN * DD;             // [8192,8192]

    char* ws = (char*)d_ws;
    size_t off = 0;
    auto alloc = [&](size_t bytes) { void* p = ws + off; off += (bytes + 255) & ~(size_t)255; return p; };
    bf16_t* x_b   = (bf16_t*)alloc((size_t)NN * FIN * 2);    // 8 MB
    bf16_t* w1t   = (bf16_t*)alloc((size_t)HD * FIN * 2);    // 256 KB  [H][FIN]
    bf16_t* w2t   = (bf16_t*)alloc((size_t)DD * HD * 2);     // 32 KB   [D][H]
    bf16_t* h0    = (bf16_t*)alloc((size_t)NN * HD * 2);     // 4 MB
    bf16_t* h_b   = (bf16_t*)alloc((size_t)NN * HD * 2);     // 4 MB
    bf16_t* z0    = (bf16_t*)alloc((size_t)NN * DD * 2);     // 1 MB
    bf16_t* z_b   = (bf16_t*)alloc((size_t)NN * DD * 2);     // 1 MB
    int* deg      = (int*)alloc((size_t)NN * 4);             // 32 KB
    int* scol     = (int*)alloc((size_t)NN * BCAP * 4);      // 4 MB
    float* sval   = (float*)alloc((size_t)NN * BCAP * 4);    // 4 MB

    // prep: cast x, transpose W1/W2, zero deg (vectorized stores)
    prep_kernel<<<2048 + 128 + 16 + 8, 256, 0, stream>>>(x, x_b, W1, w1t, W2, w2t, deg);

    // fused: GEMM1 (512 tiles) + bucket scatter (1024 blocks)
    gemm1_scatter<<<512 + 1024, 256, 0, stream>>>(x_b, w1t, b1, h0,
                                                  rows, cols, vals, deg, scol, sval);

    // SpMM1 + relu -> bf16
    spmm_h_kernel<<<NN, 256, 0, stream>>>(deg, scol, sval, h0, h_b);

    // GEMM2: z0 = h @ W2 + b2  (bf16 out)
    gemm_bt<0, bf16_t, 1><<<dim3(NN / 64, DD / 64), 256, 0, stream>>>(h_b, w2t, b2, z0, NN, DD, HD);

    // SpMM2 -> z (fp32) + bf16 copy, vectorized
    spmm_z_kernel<<<NN / 16, 256, 0, stream>>>(deg, scol, sval, z0, out_z, z_b);

    // GEMM3: adj_rec = sigmoid(z @ z^T)  tile 128x64, LDS-transposed float4 stores
    gemm_bt<2, float, 2><<<dim3(NN / 128, NN / 64), 256, 0, stream>>>(z_b, z_b, nullptr, out_adj, NN, NN, DD);
}